// Round 4
// baseline (437.050 us; speedup 1.0000x reference)
//
#include <hip/hip_runtime.h>
#include <stdint.h>

typedef uint16_t u16;
typedef uint32_t u32;
typedef __attribute__((ext_vector_type(8)))  __bf16 bf16x8;
typedef __attribute__((ext_vector_type(16))) float  f32x16;
typedef __attribute__((ext_vector_type(4)))  float  f32x4;
typedef __attribute__((ext_vector_type(2)))  u32    u32x2;

#define NROWS   100000
#define E_EDGES 3200000
#define ROWS_PB 128           // rows per block (4 row-tiles of 32)
#define NBLK    782           // ceil(100000/128)

// LDS activation tile: H[128 rows][256 cols] bf16, XOR-swizzled on 8-elem (16B)
// granules: elem offset = row*256 + ((g ^ (row&31))<<3) + e   (g = col>>3)
#define HIDX(r, g) (((r) << 8) + ((((g) ^ ((r) & 31))) << 3))

#define MFMA(a, b, c) __builtin_amdgcn_mfma_f32_32x32x16_bf16((a), (b), (c), 0, 0, 0)

// pack two f32 -> bf16x2 via plain casts (compiler emits v_cvt_pk_bf16_f32, RNE)
__device__ __forceinline__ u32 bfpack(float a, float b) {
    u16 lo = __builtin_bit_cast(u16, (__bf16)a);
    u16 hi = __builtin_bit_cast(u16, (__bf16)b);
    return (u32)lo | ((u32)hi << 16);
}
// tanh(x) = 1 - 2/(exp2(x*2*log2e)+1): mul, exp2, add, rcp, fma
__device__ __forceinline__ float fast_tanh(float x) {
    float e = __builtin_amdgcn_exp2f(x * 2.885390081777927f);
    float r = __builtin_amdgcn_rcpf(e + 1.0f);
    return __builtin_fmaf(-2.0f, r, 1.0f);
}
__device__ __forceinline__ float fast_sigmoid(float x) {
    float e = __builtin_amdgcn_exp2f(x * -1.4426950408889634f);
    return __builtin_amdgcn_rcpf(1.0f + e);
}

// One 256->256 layer + bias + tanh, in place on Hs (128 rows).
// 8 waves/block; wave = (row-pair rb/64, n-pair nw).  Wave owns n-tiles
// {2nw, 2nw+1} x row-tiles {rb/32, rb/32+1}: acc[4] (64 AGPR).  Per-wave
// balance identical to the proven 64-row version (2 weight loads + 2
// ds_read_b128 per 4 MFMA = LDS at its 256B/cyc/CU balance point at full
// MFMA rate).  Weights stream from L2, prefetched 3 K-steps ahead; H frags
// 2 steps ahead.  Weight preloads issue BEFORE the barrier so they fly
// during the barrier wait.  s_setprio(1) around the MFMA cluster (T5 --
// waves here are phase-decorrelated, the regime where it measured +4-7%).
// WB layout: [step 16][n 256][kloc 16] bf16 (k = s*16 + kloc), step stride 4096.
__device__ __forceinline__ void dense256(u16* __restrict__ Hs, const u16* __restrict__ WB,
                                         const float* __restrict__ bias,
                                         int nw, int rb, int l31, int lh) {
    f32x16 acc[4];
#pragma unroll
    for (int i = 0; i < 4; ++i)
#pragma unroll
        for (int j = 0; j < 16; ++j) acc[i][j] = 0.0f;

    const u16* wp = WB + (nw * 64 + l31) * 16 + lh * 8;   // n-tile 2nw; +512 -> 2nw+1
    bf16x8 wq0[3], wq1[3];
#pragma unroll
    for (int d = 0; d < 3; ++d) {          // in flight during the barrier wait
        wq0[d] = *(const bf16x8*)(wp + d * 4096);
        wq1[d] = *(const bf16x8*)(wp + d * 4096 + 512);
    }

    __syncthreads();   // H writes from previous phase visible

    bf16x8 hq0[2], hq1[2];
#pragma unroll
    for (int d = 0; d < 2; ++d) {
        const int g = 2 * d + lh;
        hq0[d] = *(const bf16x8*)(Hs + HIDX(rb + l31, g));
        hq1[d] = *(const bf16x8*)(Hs + HIDX(rb + 32 + l31, g));
    }

#pragma unroll
    for (int s = 0; s < 16; ++s) {
        const int cw = s % 3, ch = s & 1;
        bf16x8 w0 = wq0[cw], w1 = wq1[cw], h0 = hq0[ch], h1 = hq1[ch];
        if (s + 3 < 16) {
            wq0[cw] = *(const bf16x8*)(wp + (s + 3) * 4096);
            wq1[cw] = *(const bf16x8*)(wp + (s + 3) * 4096 + 512);
        }
        if (s + 2 < 16) {
            const int ng = 2 * (s + 2) + lh;
            hq0[ch] = *(const bf16x8*)(Hs + HIDX(rb + l31, ng));
            hq1[ch] = *(const bf16x8*)(Hs + HIDX(rb + 32 + l31, ng));
        }
        __builtin_amdgcn_s_setprio(1);
        acc[0] = MFMA(w0, h0, acc[0]);
        acc[1] = MFMA(w0, h1, acc[1]);
        acc[2] = MFMA(w1, h0, acc[2]);
        acc[3] = MFMA(w1, h1, acc[3]);
        __builtin_amdgcn_s_setprio(0);
    }
    __syncthreads();   // all H reads done before in-place overwrite

    // epilogue: bias + tanh + packed write-back (4 consecutive neurons per reg-quad)
#pragma unroll
    for (int i = 0; i < 2; ++i) {
        const int nt = nw * 2 + i;
#pragma unroll
        for (int rg = 0; rg < 4; ++rg) {
            const float4 bv = *(const float4*)(bias + nt * 32 + rg * 8 + lh * 4);
#pragma unroll
            for (int b = 0; b < 2; ++b) {
                const f32x16& A = acc[i * 2 + b];
                float x0 = fast_tanh(A[rg * 4 + 0] + bv.x);
                float x1 = fast_tanh(A[rg * 4 + 1] + bv.y);
                float x2 = fast_tanh(A[rg * 4 + 2] + bv.z);
                float x3 = fast_tanh(A[rg * 4 + 3] + bv.w);
                const int r = rb + b * 32 + l31;         // batch row (C/D col)
                const int g = nt * 4 + rg;               // neuron granule
                uint2 v; v.x = bfpack(x0, x1); v.y = bfpack(x2, x3);
                *(uint2*)(Hs + (r << 8) + (((g) ^ (r & 31)) << 3) + lh * 4) = v;
            }
        }
    }
}

// final 256->32(padded) layer; waves 0..3 each take one 32-row batch tile.
// WBf layout: [step 16][n 32][kloc 16], step stride 512.  2-deep prefetch.
__device__ __forceinline__ f32x16 final_dense(const u16* __restrict__ Hs,
                                              const u16* __restrict__ WBf,
                                              int wave, int l31, int lh) {
    __syncthreads();   // H ready
    f32x16 acc;
#pragma unroll
    for (int j = 0; j < 16; ++j) acc[j] = 0.0f;
    if (wave < 4) {
        const u16* wp = WBf + l31 * 16 + lh * 8;
        bf16x8 wq[2], hq[2];
#pragma unroll
        for (int d = 0; d < 2; ++d) {
            wq[d] = *(const bf16x8*)(wp + d * 512);
            hq[d] = *(const bf16x8*)(Hs + HIDX(wave * 32 + l31, 2 * d + lh));
        }
#pragma unroll
        for (int s = 0; s < 16; ++s) {
            const int c = s & 1;
            bf16x8 w = wq[c], h = hq[c];
            if (s + 2 < 16) {
                wq[c] = *(const bf16x8*)(wp + (s + 2) * 512);
                hq[c] = *(const bf16x8*)(Hs + HIDX(wave * 32 + l31, 2 * (s + 2) + lh));
            }
            acc = MFMA(w, h, acc);
        }
    }
    return acc;
}

__global__ __launch_bounds__(512, 4) void mlp1_kernel(
    const float* __restrict__ ea, const u16* __restrict__ WB1, const u16* __restrict__ WB13,
    const float* __restrict__ b0, const float* __restrict__ b1, const float* __restrict__ b2,
    const float* __restrict__ b3, u16* __restrict__ out1) {
    __shared__ u16 Hs[ROWS_PB * 256];   // 64 KB -> 2 blocks/CU, 16 waves/CU
    const int tid = threadIdx.x, wave = tid >> 6, lane = tid & 63, blk = blockIdx.x;
    const int l31 = lane & 31, lh = lane >> 5;
    const int nw = wave & 3, rb = (wave >> 2) * 64;

    // stage A = edge_attr rows: coalesced 32B/lane, nontemporal (the whole-grid
    // edge_attr stream is larger than L2 -- don't evict the weight lines), cvt bf16
#pragma unroll
    for (int i = 0; i < 8; ++i) {
        const int li = i * 512 + tid;           // 0..4095 granule tasks
        const int r = li >> 5, g = li & 31;
        const int rg_ = blk * ROWS_PB + r;
        uint4 v = {0u, 0u, 0u, 0u};
        if (rg_ < NROWS) {
            const float* p = ea + (size_t)rg_ * 256 + g * 8;
            f32x4 a0 = __builtin_nontemporal_load((const f32x4*)p);
            f32x4 a1 = __builtin_nontemporal_load((const f32x4*)p + 1);
            v.x = bfpack(a0.x, a0.y); v.y = bfpack(a0.z, a0.w);
            v.z = bfpack(a1.x, a1.y); v.w = bfpack(a1.z, a1.w);
        }
        *(uint4*)(Hs + HIDX(r, g)) = v;
    }
    dense256(Hs, WB1,          b0, nw, rb, l31, lh);
    dense256(Hs, WB1 + 65536,  b1, nw, rb, l31, lh);
    dense256(Hs, WB1 + 131072, b2, nw, rb, l31, lh);
    f32x16 acc = final_dense(Hs, WB13, wave, l31, lh);

    if (wave < 4) {
        const int row_g = blk * ROWS_PB + wave * 32 + l31;
        if (row_g < NROWS) {
            if (lh == 0) {           // neurons 0..3 in regs 0..3
                float s0 = fast_sigmoid(acc[0] + b3[0]);
                float s1 = fast_sigmoid(acc[1] + b3[1]);
                float s2 = fast_sigmoid(acc[2] + b3[2]);
                float s3 = fast_sigmoid(acc[3] + b3[3]);
                u32x2 v; v.x = bfpack(s0, s1); v.y = bfpack(s2, s3);
                __builtin_nontemporal_store(v, (u32x2*)(out1 + (size_t)row_g * 8));
            } else {                 // neuron 4 in reg 0; zero-pad 5..7
                float s4 = fast_sigmoid(acc[0] + b3[4]);
                u32x2 v; v.x = bfpack(s4, 0.0f); v.y = 0u;
                __builtin_nontemporal_store(v, (u32x2*)(out1 + (size_t)row_g * 8 + 4));
            }
        }
    }
}

__global__ __launch_bounds__(512, 4) void mlp2_kernel(
    const int* __restrict__ idx1, const u16* __restrict__ out1,
    const u16* __restrict__ WB2, const u16* __restrict__ WB23,
    const float* __restrict__ b0, const float* __restrict__ b1, const float* __restrict__ b2,
    const float* __restrict__ b3, float* __restrict__ out) {
    __shared__ u16 Hs[ROWS_PB * 256];
    const int tid = threadIdx.x, wave = tid >> 6, lane = tid & 63, blk = blockIdx.x;
    const int l31 = lane & 31, lh = lane >> 5;
    const int nw = wave & 3, rb = (wave >> 2) * 64;

    // gather: 4096 edges/block; nontemporal index stream, then 8 gathers in
    // flight per lane (out1 is 1.6MB -> L2-resident, keep those cached)
    int nodes[8];
#pragma unroll
    for (int i = 0; i < 8; ++i) {
        const long e = (long)blk * 4096 + i * 512 + tid;
        nodes[i] = (e < (long)E_EDGES) ? __builtin_nontemporal_load(idx1 + e) : -1;
    }
#pragma unroll
    for (int i = 0; i < 8; ++i) {
        const int li = i * 512 + tid;           // 0..4095
        const int r = li >> 5, j = li & 31;
        uint4 v = {0u, 0u, 0u, 0u};
        if (nodes[i] >= 0) v = *(const uint4*)(out1 + (size_t)nodes[i] * 8);
        *(uint4*)(Hs + HIDX(r, j)) = v;
    }
    dense256(Hs, WB2,          b0, nw, rb, l31, lh);   // K padded 160->256, zero weights
    dense256(Hs, WB2 + 65536,  b1, nw, rb, l31, lh);
    dense256(Hs, WB2 + 131072, b2, nw, rb, l31, lh);
    f32x16 acc = final_dense(Hs, WB23, wave, l31, lh);

    if (wave < 4) {
        const int row_g = blk * ROWS_PB + wave * 32 + l31;
        if (row_g < NROWS && lh == 0)
            __builtin_nontemporal_store(fast_sigmoid(acc[0] + b3[0]), out + row_g);
    }
}

// Build all bf16 blocked weight layouts in workspace (once per launch).
// Layouts: WB [step 16][n N][kloc 16], k = step*16 + kloc.
__global__ void transform_kernel(
    const float* __restrict__ w10, const float* __restrict__ w11, const float* __restrict__ w12,
    const float* __restrict__ w13, const float* __restrict__ w20, const float* __restrict__ w21,
    const float* __restrict__ w22, const float* __restrict__ w23, u16* __restrict__ ws) {
    const int id = blockIdx.x * 256 + threadIdx.x;   // 409600 outputs
    float val;
    if (id < 196608) {                         // WB1: 3 layers [16][256][16]
        int layer = id >> 16, rem = id & 65535;
        int s = rem >> 12, n = (rem >> 4) & 255, kl = rem & 15;
        int k = s * 16 + kl;
        const float* w = layer == 0 ? w10 : (layer == 1 ? w11 : w12);
        val = w[k * 256 + n];
    } else if (id < 204800) {                  // WB13: [16][32][16], n>=5 zero
        int rem = id - 196608;
        int s = rem >> 9, n = (rem >> 4) & 31, kl = rem & 15;
        int k = s * 16 + kl;
        val = (n < 5) ? w13[k * 5 + n] : 0.0f;
    } else if (id < 401408) {                  // WB2: 3 layers; layer0 K 160->256 expanded
        int rem = id - 204800;
        int layer = rem >> 16; rem &= 65535;
        int s = rem >> 12, n = (rem >> 4) & 255, kl = rem & 15;
        int k = s * 16 + kl;
        if (layer == 0) {
            int j = k >> 3, v = k & 7;
            val = (v < 5) ? w20[(j * 5 + v) * 256 + n] : 0.0f;
        } else {
            val = (layer == 1 ? w21 : w22)[k * 256 + n];
        }
    } else {                                   // WB23: [16][32][16], n!=0 zero
        int rem = id - 401408;
        int s = rem >> 9, n = (rem >> 4) & 31, kl = rem & 15;
        int k = s * 16 + kl;
        val = (n == 0) ? w23[k] : 0.0f;
    }
    u32 u = __builtin_bit_cast(u32, val);
    u = (u + 0x7FFFu + ((u >> 16) & 1u)) >> 16;   // RNE
    ws[id] = (u16)u;
}

extern "C" void kernel_launch(void* const* d_in, const int* in_sizes, int n_in,
                              void* d_out, int out_size, void* d_ws, size_t ws_size,
                              hipStream_t stream) {
    const int*   ei  = (const int*)d_in[1];     // edge_index [2][E] int32
    const float* ea  = (const float*)d_in[2];   // edge_attr [E][8] f32
    const float* w10 = (const float*)d_in[3];  const float* b10 = (const float*)d_in[4];
    const float* w11 = (const float*)d_in[5];  const float* b11 = (const float*)d_in[6];
    const float* w12 = (const float*)d_in[7];  const float* b12 = (const float*)d_in[8];
    const float* w13 = (const float*)d_in[9];  const float* b13 = (const float*)d_in[10];
    const float* w20 = (const float*)d_in[11]; const float* b20 = (const float*)d_in[12];
    const float* w21 = (const float*)d_in[13]; const float* b21 = (const float*)d_in[14];
    const float* w22 = (const float*)d_in[15]; const float* b22 = (const float*)d_in[16];
    const float* w23 = (const float*)d_in[17]; const float* b23 = (const float*)d_in[18];

    u16* ws   = (u16*)d_ws;            // u16-unit offsets
    u16* WB1  = ws;                    // 196608
    u16* WB13 = ws + 196608;           // 8192
    u16* WB2  = ws + 204800;           // 196608
    u16* WB23 = ws + 401408;           // 8192
    u16* out1 = ws + 409600;           // 100000 x 8 bf16 (padded rows)

    hipLaunchKernelGGL(transform_kernel, dim3(1600), dim3(256), 0, stream,
                       w10, w11, w12, w13, w20, w21, w22, w23, ws);
    hipLaunchKernelGGL(mlp1_kernel, dim3(NBLK), dim3(512), 0, stream,
                       ea, WB1, WB13, b10, b11, b12, b13, out1);
    hipLaunchKernelGGL(mlp2_kernel, dim3(NBLK), dim3(512), 0, stream,
                       ei + E_EDGES, out1, WB2, WB23, b20, b21, b22, b23, (float*)d_out);
}

// Round 5
// 319.253 us; speedup vs baseline: 1.3690x; 1.3690x over previous
//
#include <hip/hip_runtime.h>
#include <stdint.h>

typedef uint16_t u16;
typedef uint32_t u32;
typedef __attribute__((ext_vector_type(8)))  __bf16 bf16x8;
typedef __attribute__((ext_vector_type(16))) float  f32x16;
typedef __attribute__((ext_vector_type(4)))  float  f32x4;
typedef __attribute__((ext_vector_type(2)))  u32    u32x2;

#define NROWS   100000
#define E_EDGES 3200000

// LDS activation tile: H[64 rows][256 cols] bf16, XOR-swizzled on 8-elem (16B)
// granules: elem offset = row*256 + ((g ^ (row&31))<<3) + e   (g = col>>3)
#define HIDX(r, g) (((r) << 8) + ((((g) ^ ((r) & 31))) << 3))

#define MFMA(a, b, c) __builtin_amdgcn_mfma_f32_32x32x16_bf16((a), (b), (c), 0, 0, 0)

// pack two f32 -> bf16x2 via plain casts (compiler emits v_cvt_pk_bf16_f32, RNE)
__device__ __forceinline__ u32 bfpack(float a, float b) {
    u16 lo = __builtin_bit_cast(u16, (__bf16)a);
    u16 hi = __builtin_bit_cast(u16, (__bf16)b);
    return (u32)lo | ((u32)hi << 16);
}
// tanh(x) = 1 - 2/(exp2(x*2*log2e)+1): mul, exp2, add, rcp, fma
__device__ __forceinline__ float fast_tanh(float x) {
    float e = __builtin_amdgcn_exp2f(x * 2.885390081777927f);
    float r = __builtin_amdgcn_rcpf(e + 1.0f);
    return __builtin_fmaf(-2.0f, r, 1.0f);
}
__device__ __forceinline__ float fast_sigmoid(float x) {
    float e = __builtin_amdgcn_exp2f(x * -1.4426950408889634f);
    return __builtin_amdgcn_rcpf(1.0f + e);
}

// One 256->256 layer + bias + tanh, in place on Hs (64 rows).
// 4 waves/block; wave owns n-tiles {2w, 2w+1} x batch-tiles {0,1}: acc[4] (64 AGPR).
// Weights stream from L2, prefetched 3 K-steps ahead; H frags 2 steps ahead.
// Weight preloads issue BEFORE the barrier so they fly during the barrier wait.
// NEW: per-wave-contiguous weight slabs -- WB[layer][nw][t][s][l31][lh][8]
// (u16 strides: nw 16384, t 8192, s 512, l31 16, lh 8).  The per-step loads are
// base + t*16KB + s*1KB: compile-time-foldable offsets from ONE base (kills the
// per-step 64-bit address adds that made VALUBusy > MfmaUtil), still fully
// coalesced per instruction (wave covers a contiguous 1KB), and the wave streams
// its 32KB slab sequentially (L1/prefetch friendly).
__device__ __forceinline__ void dense256(u16* __restrict__ Hs, const u16* __restrict__ WB,
                                         const float* __restrict__ bias,
                                         int wave, int l31, int lh) {
    f32x16 acc[4];
#pragma unroll
    for (int i = 0; i < 4; ++i)
#pragma unroll
        for (int j = 0; j < 16; ++j) acc[i][j] = 0.0f;

    const u16* wp = WB + wave * 16384 + l31 * 16 + lh * 8;   // wave slab base
    bf16x8 wq0[3], wq1[3];
#pragma unroll
    for (int d = 0; d < 3; ++d) {          // in flight during the barrier wait
        wq0[d] = *(const bf16x8*)(wp + d * 512);           // n-tile 2w,   step d
        wq1[d] = *(const bf16x8*)(wp + 8192 + d * 512);    // n-tile 2w+1, step d
    }

    __syncthreads();   // H writes from previous phase visible

    bf16x8 hq0[2], hq1[2];
#pragma unroll
    for (int d = 0; d < 2; ++d) {
        const int g = 2 * d + lh;
        hq0[d] = *(const bf16x8*)(Hs + HIDX(l31, g));
        hq1[d] = *(const bf16x8*)(Hs + HIDX(32 + l31, g));
    }

#pragma unroll
    for (int s = 0; s < 16; ++s) {
        const int cw = s % 3, ch = s & 1;
        bf16x8 w0 = wq0[cw], w1 = wq1[cw], h0 = hq0[ch], h1 = hq1[ch];
        if (s + 3 < 16) {
            wq0[cw] = *(const bf16x8*)(wp + (s + 3) * 512);
            wq1[cw] = *(const bf16x8*)(wp + 8192 + (s + 3) * 512);
        }
        if (s + 2 < 16) {
            const int ng = 2 * (s + 2) + lh;
            hq0[ch] = *(const bf16x8*)(Hs + HIDX(l31, ng));
            hq1[ch] = *(const bf16x8*)(Hs + HIDX(32 + l31, ng));
        }
        acc[0] = MFMA(w0, h0, acc[0]);
        acc[1] = MFMA(w0, h1, acc[1]);
        acc[2] = MFMA(w1, h0, acc[2]);
        acc[3] = MFMA(w1, h1, acc[3]);
    }
    __syncthreads();   // all H reads done before in-place overwrite

    // epilogue: bias + tanh + packed write-back (4 consecutive neurons per reg-quad)
#pragma unroll
    for (int i = 0; i < 2; ++i) {
        const int nt = wave * 2 + i;
#pragma unroll
        for (int rg = 0; rg < 4; ++rg) {
            const float4 bv = *(const float4*)(bias + nt * 32 + rg * 8 + lh * 4);
#pragma unroll
            for (int b = 0; b < 2; ++b) {
                const f32x16& A = acc[i * 2 + b];
                float x0 = fast_tanh(A[rg * 4 + 0] + bv.x);
                float x1 = fast_tanh(A[rg * 4 + 1] + bv.y);
                float x2 = fast_tanh(A[rg * 4 + 2] + bv.z);
                float x3 = fast_tanh(A[rg * 4 + 3] + bv.w);
                const int r = b * 32 + l31;              // batch row (C/D col)
                const int g = nt * 4 + rg;               // neuron granule
                uint2 v; v.x = bfpack(x0, x1); v.y = bfpack(x2, x3);
                *(uint2*)(Hs + (r << 8) + (((g) ^ (r & 31)) << 3) + lh * 4) = v;
            }
        }
    }
}

// final 256->32(padded) layer; waves 0..1 each take one 32-row batch tile.
// WBf layout: [step 16][n 32][kloc 16], step stride 512.  2-deep prefetch.
__device__ __forceinline__ f32x16 final_dense(const u16* __restrict__ Hs,
                                              const u16* __restrict__ WBf,
                                              int wave, int l31, int lh) {
    __syncthreads();   // H ready
    f32x16 acc;
#pragma unroll
    for (int j = 0; j < 16; ++j) acc[j] = 0.0f;
    if (wave < 2) {
        const u16* wp = WBf + l31 * 16 + lh * 8;
        bf16x8 wq[2], hq[2];
#pragma unroll
        for (int d = 0; d < 2; ++d) {
            wq[d] = *(const bf16x8*)(wp + d * 512);
            hq[d] = *(const bf16x8*)(Hs + HIDX(wave * 32 + l31, 2 * d + lh));
        }
#pragma unroll
        for (int s = 0; s < 16; ++s) {
            const int c = s & 1;
            bf16x8 w = wq[c], h = hq[c];
            if (s + 2 < 16) {
                wq[c] = *(const bf16x8*)(wp + (s + 2) * 512);
                hq[c] = *(const bf16x8*)(Hs + HIDX(wave * 32 + l31, 2 * (s + 2) + lh));
            }
            acc = MFMA(w, h, acc);
        }
    }
    return acc;
}

__global__ __launch_bounds__(256, 4) void mlp1_kernel(
    const float* __restrict__ ea, const u16* __restrict__ WB1, const u16* __restrict__ WB13,
    const float* __restrict__ b0, const float* __restrict__ b1, const float* __restrict__ b2,
    const float* __restrict__ b3, u16* __restrict__ out1) {
    __shared__ u16 Hs[64 * 256];   // 32 KB -> 4 blocks/CU (128 KB), phase-decorrelated
    const int tid = threadIdx.x, wave = tid >> 6, lane = tid & 63, blk = blockIdx.x;
    const int l31 = lane & 31, lh = lane >> 5;

    // stage A = edge_attr rows: coalesced 32B/lane, nontemporal (the whole-grid
    // edge_attr stream is larger than L2 -- don't evict the weight lines), cvt bf16
#pragma unroll
    for (int i = 0; i < 8; ++i) {
        const int li = i * 256 + tid;           // 0..2047 granule tasks
        const int r = li >> 5, g = li & 31;
        const int rg_ = blk * 64 + r;
        uint4 v = {0u, 0u, 0u, 0u};
        if (rg_ < NROWS) {
            const float* p = ea + (size_t)rg_ * 256 + g * 8;
            f32x4 a0 = __builtin_nontemporal_load((const f32x4*)p);
            f32x4 a1 = __builtin_nontemporal_load((const f32x4*)p + 1);
            v.x = bfpack(a0.x, a0.y); v.y = bfpack(a0.z, a0.w);
            v.z = bfpack(a1.x, a1.y); v.w = bfpack(a1.z, a1.w);
        }
        *(uint4*)(Hs + HIDX(r, g)) = v;
    }
    dense256(Hs, WB1,          b0, wave, l31, lh);
    dense256(Hs, WB1 + 65536,  b1, wave, l31, lh);
    dense256(Hs, WB1 + 131072, b2, wave, l31, lh);
    f32x16 acc = final_dense(Hs, WB13, wave, l31, lh);

    if (wave < 2) {
        const int row_g = blk * 64 + wave * 32 + l31;
        if (row_g < NROWS) {
            if (lh == 0) {           // neurons 0..3 in regs 0..3
                float s0 = fast_sigmoid(acc[0] + b3[0]);
                float s1 = fast_sigmoid(acc[1] + b3[1]);
                float s2 = fast_sigmoid(acc[2] + b3[2]);
                float s3 = fast_sigmoid(acc[3] + b3[3]);
                u32x2 v; v.x = bfpack(s0, s1); v.y = bfpack(s2, s3);
                __builtin_nontemporal_store(v, (u32x2*)(out1 + (size_t)row_g * 8));
            } else {                 // neuron 4 in reg 0; zero-pad 5..7
                float s4 = fast_sigmoid(acc[0] + b3[4]);
                u32x2 v; v.x = bfpack(s4, 0.0f); v.y = 0u;
                __builtin_nontemporal_store(v, (u32x2*)(out1 + (size_t)row_g * 8 + 4));
            }
        }
    }
}

__global__ __launch_bounds__(256, 4) void mlp2_kernel(
    const int* __restrict__ idx1, const u16* __restrict__ out1,
    const u16* __restrict__ WB2, const u16* __restrict__ WB23,
    const float* __restrict__ b0, const float* __restrict__ b1, const float* __restrict__ b2,
    const float* __restrict__ b3, float* __restrict__ out) {
    __shared__ u16 Hs[64 * 256];
    const int tid = threadIdx.x, wave = tid >> 6, lane = tid & 63, blk = blockIdx.x;
    const int l31 = lane & 31, lh = lane >> 5;

    // gather: 2048 edges/block; nontemporal index stream, then 8 gathers in
    // flight per lane (out1 is 1.6MB -> L2/L3-resident, keep those cached)
    int nodes[8];
#pragma unroll
    for (int i = 0; i < 8; ++i) {
        const long e = (long)blk * 2048 + i * 256 + tid;
        nodes[i] = (e < (long)E_EDGES) ? __builtin_nontemporal_load(idx1 + e) : -1;
    }
#pragma unroll
    for (int i = 0; i < 8; ++i) {
        const int li = i * 256 + tid;           // 0..2047
        const int r = li >> 5, j = li & 31;
        uint4 v = {0u, 0u, 0u, 0u};
        if (nodes[i] >= 0) v = *(const uint4*)(out1 + (size_t)nodes[i] * 8);
        *(uint4*)(Hs + HIDX(r, j)) = v;
    }
    dense256(Hs, WB2,          b0, wave, l31, lh);   // K padded 160->256, zero weights
    dense256(Hs, WB2 + 65536,  b1, wave, l31, lh);
    dense256(Hs, WB2 + 131072, b2, wave, l31, lh);
    f32x16 acc = final_dense(Hs, WB23, wave, l31, lh);

    if (wave < 2) {
        const int row_g = blk * 64 + wave * 32 + l31;
        if (row_g < NROWS && lh == 0)
            __builtin_nontemporal_store(fast_sigmoid(acc[0] + b3[0]), out + row_g);
    }
}

// Build all bf16 blocked weight layouts in workspace (once per launch).
// Dense-layer layout (WB1/WB2): [layer][nw 4][t 2][s 16][l31 32][lh 2][e 8]
//   (identity bit-decode: id2 = nw*16384 + t*8192 + s*512 + l31*16 + lh*8 + e)
//   neuron n = (2*nw + t)*32 + l31;  k = s*16 + lh*8 + e.
// Final-layer layout (WB13/WB23): [step 16][n 32][kloc 16] (unchanged).
__global__ void transform_kernel(
    const float* __restrict__ w10, const float* __restrict__ w11, const float* __restrict__ w12,
    const float* __restrict__ w13, const float* __restrict__ w20, const float* __restrict__ w21,
    const float* __restrict__ w22, const float* __restrict__ w23, u16* __restrict__ ws) {
    const int id = blockIdx.x * 256 + threadIdx.x;   // 409600 outputs
    float val;
    if (id < 196608) {                         // WB1: 3 layers, per-wave slabs
        int layer = id >> 16, id2 = id & 65535;
        int nw = id2 >> 14, t = (id2 >> 13) & 1, s = (id2 >> 9) & 15;
        int l31 = (id2 >> 4) & 31, lhe = id2 & 15;
        int n = ((nw << 1) | t) * 32 + l31;
        int k = s * 16 + lhe;                  // lhe = lh*8 + e = kloc
        const float* w = layer == 0 ? w10 : (layer == 1 ? w11 : w12);
        val = w[k * 256 + n];
    } else if (id < 204800) {                  // WB13: [16][32][16], n>=5 zero
        int rem = id - 196608;
        int s = rem >> 9, n = (rem >> 4) & 31, kl = rem & 15;
        int k = s * 16 + kl;
        val = (n < 5) ? w13[k * 5 + n] : 0.0f;
    } else if (id < 401408) {                  // WB2: 3 layers; layer0 K 160->256 expanded
        int rem = id - 204800;
        int layer = rem >> 16, id2 = rem & 65535;
        int nw = id2 >> 14, t = (id2 >> 13) & 1, s = (id2 >> 9) & 15;
        int l31 = (id2 >> 4) & 31, lhe = id2 & 15;
        int n = ((nw << 1) | t) * 32 + l31;
        int k = s * 16 + lhe;
        if (layer == 0) {
            int j = k >> 3, v = k & 7;
            val = (v < 5) ? w20[(j * 5 + v) * 256 + n] : 0.0f;
        } else {
            val = (layer == 1 ? w21 : w22)[k * 256 + n];
        }
    } else {                                   // WB23: [16][32][16], n!=0 zero
        int rem = id - 401408;
        int s = rem >> 9, n = (rem >> 4) & 31, kl = rem & 15;
        int k = s * 16 + kl;
        val = (n == 0) ? w23[k] : 0.0f;
    }
    u32 u = __builtin_bit_cast(u32, val);
    u = (u + 0x7FFFu + ((u >> 16) & 1u)) >> 16;   // RNE
    ws[id] = (u16)u;
}

extern "C" void kernel_launch(void* const* d_in, const int* in_sizes, int n_in,
                              void* d_out, int out_size, void* d_ws, size_t ws_size,
                              hipStream_t stream) {
    const int*   ei  = (const int*)d_in[1];     // edge_index [2][E] int32
    const float* ea  = (const float*)d_in[2];   // edge_attr [E][8] f32
    const float* w10 = (const float*)d_in[3];  const float* b10 = (const float*)d_in[4];
    const float* w11 = (const float*)d_in[5];  const float* b11 = (const float*)d_in[6];
    const float* w12 = (const float*)d_in[7];  const float* b12 = (const float*)d_in[8];
    const float* w13 = (const float*)d_in[9];  const float* b13 = (const float*)d_in[10];
    const float* w20 = (const float*)d_in[11]; const float* b20 = (const float*)d_in[12];
    const float* w21 = (const float*)d_in[13]; const float* b21 = (const float*)d_in[14];
    const float* w22 = (const float*)d_in[15]; const float* b22 = (const float*)d_in[16];
    const float* w23 = (const float*)d_in[17]; const float* b23 = (const float*)d_in[18];

    u16* ws   = (u16*)d_ws;            // u16-unit offsets
    u16* WB1  = ws;                    // 196608
    u16* WB13 = ws + 196608;           // 8192
    u16* WB2  = ws + 204800;           // 196608
    u16* WB23 = ws + 401408;           // 8192
    u16* out1 = ws + 409600;           // 100000 x 8 bf16 (padded rows)

    hipLaunchKernelGGL(transform_kernel, dim3(1600), dim3(256), 0, stream,
                       w10, w11, w12, w13, w20, w21, w22, w23, ws);
    hipLaunchKernelGGL(mlp1_kernel, dim3(1563), dim3(256), 0, stream,
                       ea, WB1, WB13, b10, b11, b12, b13, out1);
    hipLaunchKernelGGL(mlp2_kernel, dim3(1563), dim3(256), 0, stream,
                       ei + E_EDGES, out1, WB2, WB23, b20, b21, b22, b23, (float*)d_out);
}